// Round 1
// baseline (157.219 us; speedup 1.0000x reference)
//
#include <hip/hip_runtime.h>
#include <hip/hip_bf16.h>

#define Hd 64
#define Sd 128
#define Bd 64
#define Nn 8192
#define EPSd 1e-5f

__device__ __forceinline__ float wred_sum(float v) {
    for (int m = 32; m; m >>= 1) v += __shfl_xor(v, m);
    return v;
}
__device__ __forceinline__ int wred_sumi(int v) {
    for (int m = 32; m; m >>= 1) v += __shfl_xor(v, m);
    return v;
}
__device__ __forceinline__ float wred_max(float v) {
    for (int m = 32; m; m >>= 1) v = fmaxf(v, __shfl_xor(v, m));
    return v;
}

// K1: conv1+bn1+relu -> conv2+bn2+relu -> xf [N][64]
__global__ __launch_bounds__(256) void k1_features(
        const float* __restrict__ x,
        const float* __restrict__ c1w, const float* __restrict__ c1b,
        const float* __restrict__ b1g, const float* __restrict__ b1b,
        const float* __restrict__ b1m, const float* __restrict__ b1v,
        const float* __restrict__ c2w, const float* __restrict__ c2b,
        const float* __restrict__ b2g, const float* __restrict__ b2b,
        const float* __restrict__ b2m, const float* __restrict__ b2v,
        float* __restrict__ xf) {
    __shared__ float h1[34][64];     // [local col][cin]
    __shared__ float wT[192][64];    // [cin*3+k][cout]
    int b  = blockIdx.x >> 2;
    int s0 = (blockIdx.x & 3) * 32;
    int tid = threadIdx.x;
    // stage conv2 weights transposed
    for (int idx = tid; idx < 192 * 64; idx += 256) {
        int row = idx >> 6;          // cin*3+k
        int c   = idx & 63;
        int cin = row / 3, k = row - cin * 3;
        wT[row][c] = c2w[(c * 64 + cin) * 3 + k];
    }
    // h1 for global s in [s0-1, s0+32]
    for (int idx = tid; idx < 34 * 64; idx += 256) {
        int c   = idx & 63;
        int col = idx >> 6;
        int s   = s0 - 1 + col;
        float v = 0.f;
        if (s >= 0 && s < Sd) {
            float xm = (s > 0)      ? x[b * Sd + s - 1] : 0.f;
            float x0 = x[b * Sd + s];
            float xp = (s < Sd - 1) ? x[b * Sd + s + 1] : 0.f;
            float y  = c1w[c * 3 + 0] * xm + c1w[c * 3 + 1] * x0 + c1w[c * 3 + 2] * xp + c1b[c];
            float inv = b1g[c] * rsqrtf(b1v[c] + EPSd);
            v = fmaxf(y * inv + (b1b[c] - b1m[c] * inv), 0.f);
        }
        h1[col][c] = v;
    }
    __syncthreads();
    int c   = tid & 63;
    int sl0 = tid >> 6;
    float inv2 = b2g[c] * rsqrtf(b2v[c] + EPSd);
    float sh2  = b2b[c] - b2m[c] * inv2;
    float bias = c2b[c];
    for (int p = 0; p < 8; ++p) {
        int sl = sl0 + 4 * p;
        float acc = bias;
        #pragma unroll
        for (int cin = 0; cin < 64; ++cin) {
            #pragma unroll
            for (int k = 0; k < 3; ++k)
                acc += wT[cin * 3 + k][c] * h1[sl + k][cin];
        }
        float outv = fmaxf(acc * inv2 + sh2, 0.f);
        xf[(b * Sd + s0 + sl) * 64 + c] = outv;
    }
}

// K2: Wh = xf @ gat_W^T + gat_Wb ; s1 = Wh.a1 ; s2 = Wh.a2
__global__ __launch_bounds__(256) void k2_wh(
        const float* __restrict__ xf,
        const float* __restrict__ gW, const float* __restrict__ gWb,
        const float* __restrict__ a1, const float* __restrict__ a2,
        float* __restrict__ Wh, float* __restrict__ s1, float* __restrict__ s2) {
    __shared__ float WT[64][64];   // [k][h]
    __shared__ float xr[4][64];
    int tid = threadIdx.x;
    for (int idx = tid; idx < 4096; idx += 256) {
        int k = idx >> 6, h = idx & 63;
        WT[k][h] = gW[h * 64 + k];
    }
    int nn = tid >> 6, h = tid & 63;
    int node = blockIdx.x * 4 + nn;
    xr[nn][h] = xf[node * 64 + h];
    __syncthreads();
    float acc = gWb[h];
    #pragma unroll
    for (int k = 0; k < 64; ++k) acc += xr[nn][k] * WT[k][h];
    Wh[node * 64 + h] = acc;
    float r1 = wred_sum(acc * a1[h]);
    float r2 = wred_sum(acc * a2[h]);
    if (h == 0) { s1[node] = r1; s2[node] = r2; }
}

// K3: tmax = max(s2)
__global__ void k3_tmax(const float* __restrict__ s2, float* __restrict__ tmax) {
    __shared__ float red[256];
    int tid = threadIdx.x;
    float m = -1e30f;
    for (int i = tid; i < Nn; i += 256) m = fmaxf(m, s2[i]);
    red[tid] = m; __syncthreads();
    for (int w = 128; w; w >>= 1) {
        if (tid < w) red[tid] = fmaxf(red[tid], red[tid + w]);
        __syncthreads();
    }
    if (tid == 0) tmax[0] = red[0];
}

// K4: rank[j] = #{k : (t_k,k) < (t_j,j)}   (partial counts via atomics)
__global__ __launch_bounds__(256) void k4_rank(const float* __restrict__ s2, int* __restrict__ rank) {
    __shared__ float ts[1024];
    int jg = blockIdx.x >> 3, ch = blockIdx.x & 7;
    int tid = threadIdx.x;
    for (int idx = tid; idx < 1024; idx += 256) ts[idx] = s2[ch * 1024 + idx];
    __syncthreads();
    int j = jg * 256 + tid;
    float tj = s2[j];
    int cnt = 0, kbase = ch * 1024;
    for (int r = 0; r < 1024; ++r) {
        float tk = ts[r];
        cnt += (tk < tj) || (tk == tj && (kbase + r) < j);
    }
    atomicAdd(&rank[j], cnt);
}

// K5: scatter rows into rank order, weighted by exp(t) / exp(0.2t)
__global__ __launch_bounds__(256) void k5_scatter(
        const float* __restrict__ Wh, const float* __restrict__ s2,
        const int* __restrict__ rank,
        float* __restrict__ Rpos, float* __restrict__ Rneg,
        float* __restrict__ spos, float* __restrict__ sneg) {
    int idx = blockIdx.x * 256 + threadIdx.x;
    int j = idx >> 6, h = idx & 63;
    int r = rank[j];
    float t  = s2[j];
    float e1 = expf(t), e2 = expf(0.2f * t);
    float w = Wh[idx];
    Rpos[r * 64 + h] = e1 * w;
    Rneg[r * 64 + h] = e2 * w;
    if (h == 0) { spos[r] = e1; sneg[r] = e2; }
}

// K6: per-chunk sums (64 chunks of 128 rows)
__global__ void k6_csum(const float* __restrict__ Rpos, const float* __restrict__ Rneg,
                        const float* __restrict__ spos, const float* __restrict__ sneg,
                        float* __restrict__ csP, float* __restrict__ csN,
                        float* __restrict__ csp, float* __restrict__ csn) {
    int chunk = blockIdx.x, h = threadIdx.x;
    int base = chunk * 128;
    double aP = 0.0, aN = 0.0;
    for (int r = 0; r < 128; ++r) {
        aP += Rpos[(base + r) * 64 + h];
        aN += Rneg[(base + r) * 64 + h];
    }
    csP[chunk * 64 + h] = (float)aP;
    csN[chunk * 64 + h] = (float)aN;
    if (h == 0) { double a = 0.0; for (int r = 0; r < 128; ++r) a += spos[base + r]; csp[chunk] = (float)a; }
    if (h == 1) { double a = 0.0; for (int r = 0; r < 128; ++r) a += sneg[base + r]; csn[chunk] = (float)a; }
}

// K7: exclusive scan of chunk sums (in place)
__global__ void k7_scan(float* __restrict__ csP, float* __restrict__ csN,
                        float* __restrict__ csp, float* __restrict__ csn) {
    int h = threadIdx.x;
    double acc = 0.0;
    for (int ch = 0; ch < 64; ++ch) { float v = csP[ch * 64 + h]; csP[ch * 64 + h] = (float)acc; acc += v; }
    acc = 0.0;
    for (int ch = 0; ch < 64; ++ch) { float v = csN[ch * 64 + h]; csN[ch * 64 + h] = (float)acc; acc += v; }
    if (h == 0) { double a = 0.0; for (int ch = 0; ch < 64; ++ch) { float v = csp[ch]; csp[ch] = (float)a; a += v; } }
    if (h == 1) { double a = 0.0; for (int ch = 0; ch < 64; ++ch) { float v = csn[ch]; csn[ch] = (float)a; a += v; } }
}

// K8: expand to full exclusive prefixes; row Nn = totals
__global__ void k8_expand(const float* __restrict__ Rpos, const float* __restrict__ Rneg,
                          const float* __restrict__ spos, const float* __restrict__ sneg,
                          const float* __restrict__ csP, const float* __restrict__ csN,
                          const float* __restrict__ csp, const float* __restrict__ csn,
                          float* __restrict__ Ppos, float* __restrict__ Pneg,
                          float* __restrict__ ppos, float* __restrict__ pneg) {
    int chunk = blockIdx.x, h = threadIdx.x;
    int base = chunk * 128;
    double runP = csP[chunk * 64 + h];
    double runN = csN[chunk * 64 + h];
    for (int r = 0; r < 128; ++r) {
        int idx = base + r;
        Ppos[idx * 64 + h] = (float)runP; runP += Rpos[idx * 64 + h];
        Pneg[idx * 64 + h] = (float)runN; runN += Rneg[idx * 64 + h];
    }
    if (chunk == 63) { Ppos[Nn * 64 + h] = (float)runP; Pneg[Nn * 64 + h] = (float)runN; }
    if (h == 0) {
        double rp = csp[chunk];
        for (int r = 0; r < 128; ++r) { int idx = base + r; ppos[idx] = (float)rp; rp += spos[idx]; }
        if (chunk == 63) ppos[Nn] = (float)rp;
    }
    if (h == 1) {
        double rn = csn[chunk];
        for (int r = 0; r < 128; ++r) { int idx = base + r; pneg[idx] = (float)rn; rn += sneg[idx]; }
        if (chunk == 63) pneg[Nn] = (float)rn;
    }
}

// K9: per-node hp via split prefix sums, then time-attention weighting -> h2
__global__ __launch_bounds__(64) void k9_node(
        const float* __restrict__ s1, const float* __restrict__ s2,
        const float* __restrict__ tmaxp, const float* __restrict__ abp,
        const float* __restrict__ Ppos, const float* __restrict__ Pneg,
        const float* __restrict__ ppos, const float* __restrict__ pneg,
        const float* __restrict__ taW, const float* __restrict__ tab,
        float* __restrict__ h2) {
    __shared__ float hl[64];
    int i = blockIdx.x, lane = threadIdx.x;
    float c = s1[i] + abp[0];
    float negc = -c;
    int cnt = 0;
    for (int r = 0; r < 128; ++r) {
        float t = s2[lane + 64 * r];
        cnt += (t <= negc) ? 1 : 0;
    }
    int k = wred_sumi(cnt);         // |{j: t_j <= -c}| -> head length
    float tmx = tmaxp[0];
    float z = c + tmx;
    float m = (z >= 0.f) ? z : 0.2f * z;   // max_j e_ij
    float E1 = expf(c - m), E2 = expf(0.2f * c - m);
    float Pp = Ppos[k * 64 + lane], Pn = Pneg[k * 64 + lane];
    float Tp = Ppos[Nn * 64 + lane];
    float num = E1 * (Tp - Pp) + E2 * Pn;
    float den = E1 * (ppos[Nn] - ppos[k]) + E2 * pneg[k];
    float hp = num / den;
    hl[lane] = hp;
    __syncthreads();
    float v = tab[lane];
    #pragma unroll
    for (int kk = 0; kk < 64; ++kk) v += taW[lane * 64 + kk] * hl[kk];
    float mx = wred_max(v);
    float e = expf(v - mx);
    float ssum = wred_sum(e);
    h2[i * 64 + lane] = hp * (e / ssum);
}

// K10: mean over S
__global__ void k10_pool(const float* __restrict__ h2, float* __restrict__ pooled) {
    int b = blockIdx.x, h = threadIdx.x;
    float acc = 0.f;
    for (int s = 0; s < Sd; ++s) acc += h2[(b * Sd + s) * 64 + h];
    pooled[b * 64 + h] = acc * (1.f / 128.f);
}

// K11: MLP head
__global__ void k11_mlp(const float* __restrict__ pooled,
                        const float* __restrict__ p1W, const float* __restrict__ p1b,
                        const float* __restrict__ p2W, const float* __restrict__ p2b,
                        float* __restrict__ out) {
    int b = blockIdx.x, q = threadIdx.x;
    float val = 0.f;
    if (q < 32) {
        float acc = p1b[q];
        for (int k = 0; k < 64; ++k) acc += p1W[q * 64 + k] * pooled[b * 64 + k];
        val = p2W[q] * fmaxf(acc, 0.f);
    }
    val = wred_sum(val);
    if (q == 0) out[b] = val + p2b[0];
}

extern "C" void kernel_launch(void* const* d_in, const int* in_sizes, int n_in,
                              void* d_out, int out_size, void* d_ws, size_t ws_size,
                              hipStream_t stream) {
    const float* x    = (const float*)d_in[0];
    const float* c1w  = (const float*)d_in[1];
    const float* c1b  = (const float*)d_in[2];
    const float* b1g  = (const float*)d_in[3];
    const float* b1b  = (const float*)d_in[4];
    const float* b1m  = (const float*)d_in[5];
    const float* b1v  = (const float*)d_in[6];
    const float* c2w  = (const float*)d_in[7];
    const float* c2b  = (const float*)d_in[8];
    const float* b2g  = (const float*)d_in[9];
    const float* b2b  = (const float*)d_in[10];
    const float* b2m  = (const float*)d_in[11];
    const float* b2v  = (const float*)d_in[12];
    const float* gW   = (const float*)d_in[13];
    const float* gWb  = (const float*)d_in[14];
    const float* ga1  = (const float*)d_in[15];
    const float* ga2  = (const float*)d_in[16];
    const float* gab  = (const float*)d_in[17];
    const float* taW  = (const float*)d_in[18];
    const float* tab  = (const float*)d_in[19];
    const float* p1W  = (const float*)d_in[20];
    const float* p1b  = (const float*)d_in[21];
    const float* p2W  = (const float*)d_in[22];
    const float* p2b  = (const float*)d_in[23];
    float* out = (float*)d_out;

    float* ws   = (float*)d_ws;
    float* xf   = ws;                      // 524288
    float* Wh   = xf + 524288;             // 524288
    float* s1   = Wh + 524288;             // 8192
    float* s2v  = s1 + 8192;               // 8192
    float* tmx  = s2v + 8192;              // 64 (padded)
    int*   rnk  = (int*)(tmx + 64);        // 8192 ints
    float* spos = (float*)(rnk + 8192);    // 8192
    float* sneg = spos + 8192;             // 8192
    float* Rpos = sneg + 8192;             // 524288
    float* Rneg = Rpos + 524288;           // 524288
    float* Ppos = Rneg + 524288;           // 524352 (8193 rows)
    float* Pneg = Ppos + 524352;           // 524352
    float* ppos = Pneg + 524352;           // 8200 (padded)
    float* pneg = ppos + 8200;             // 8200
    float* csP  = pneg + 8200;             // 4096
    float* csN  = csP + 4096;              // 4096
    float* csp  = csN + 4096;              // 64
    float* csn  = csp + 64;                // 64
    float* h2   = Rpos;                    // alias (Rpos dead after K8)
    float* pooled = Rneg;                  // alias (Rneg dead after K8)

    k1_features<<<256, 256, 0, stream>>>(x, c1w, c1b, b1g, b1b, b1m, b1v,
                                         c2w, c2b, b2g, b2b, b2m, b2v, xf);
    k2_wh<<<2048, 256, 0, stream>>>(xf, gW, gWb, ga1, ga2, Wh, s1, s2v);
    k3_tmax<<<1, 256, 0, stream>>>(s2v, tmx);
    hipMemsetAsync(rnk, 0, 8192 * sizeof(int), stream);
    k4_rank<<<256, 256, 0, stream>>>(s2v, rnk);
    k5_scatter<<<2048, 256, 0, stream>>>(Wh, s2v, rnk, Rpos, Rneg, spos, sneg);
    k6_csum<<<64, 64, 0, stream>>>(Rpos, Rneg, spos, sneg, csP, csN, csp, csn);
    k7_scan<<<1, 64, 0, stream>>>(csP, csN, csp, csn);
    k8_expand<<<64, 64, 0, stream>>>(Rpos, Rneg, spos, sneg, csP, csN, csp, csn,
                                     Ppos, Pneg, ppos, pneg);
    k9_node<<<Nn, 64, 0, stream>>>(s1, s2v, tmx, gab, Ppos, Pneg, ppos, pneg, taW, tab, h2);
    k10_pool<<<64, 64, 0, stream>>>(h2, pooled);
    k11_mlp<<<64, 64, 0, stream>>>(pooled, p1W, p1b, p2W, p2b, out);
}

// Round 2
// 96.818 us; speedup vs baseline: 1.6239x; 1.6239x over previous
//
#include <hip/hip_runtime.h>
#include <hip/hip_bf16.h>

#define Hd 64
#define Sd 128
#define Bd 64
#define Nn 8192
#define EPSd 1e-5f

__device__ __forceinline__ float wred_sum(float v) {
    for (int m = 32; m; m >>= 1) v += __shfl_xor(v, m);
    return v;
}
__device__ __forceinline__ float wred_max(float v) {
    for (int m = 32; m; m >>= 1) v = fmaxf(v, __shfl_xor(v, m));
    return v;
}

// K1: conv1+bn1+relu -> conv2+bn2+relu -> xf [N][64]
// block: (b, s0) quadrant of 32 seq positions; float4-vectorized conv2.
__global__ __launch_bounds__(256) void k1_features(
        const float* __restrict__ x,
        const float* __restrict__ c1w, const float* __restrict__ c1b,
        const float* __restrict__ b1g, const float* __restrict__ b1b,
        const float* __restrict__ b1m, const float* __restrict__ b1v,
        const float* __restrict__ c2w, const float* __restrict__ c2b,
        const float* __restrict__ b2g, const float* __restrict__ b2b,
        const float* __restrict__ b2m, const float* __restrict__ b2v,
        float* __restrict__ xf) {
    __shared__ float h1[34 * 64];      // [col][cin]
    __shared__ float wtk[3 * 16 * 64 * 4];  // float4 view: [(k*16+cin4)*64 + c]
    int b  = blockIdx.x >> 2;
    int s0 = (blockIdx.x & 3) * 32;
    int tid = threadIdx.x;
    // stage conv2 weights: flat idx = (k*16+cin4)*256 + c*4 + j
    for (int idx = tid; idx < 12288; idx += 256) {
        int j    = idx & 3;
        int c    = (idx >> 2) & 63;
        int cin4 = (idx >> 8) & 15;
        int k    = idx >> 12;
        wtk[idx] = c2w[(c * 64 + cin4 * 4 + j) * 3 + k];
    }
    // h1 for global s in [s0-1, s0+32]
    for (int idx = tid; idx < 34 * 64; idx += 256) {
        int cin = idx & 63;
        int col = idx >> 6;
        int s   = s0 - 1 + col;
        float v = 0.f;
        if (s >= 0 && s < Sd) {
            float xm = (s > 0)      ? x[b * Sd + s - 1] : 0.f;
            float x0 = x[b * Sd + s];
            float xp = (s < Sd - 1) ? x[b * Sd + s + 1] : 0.f;
            float y  = c1w[cin * 3 + 0] * xm + c1w[cin * 3 + 1] * x0 + c1w[cin * 3 + 2] * xp + c1b[cin];
            float inv = b1g[cin] * rsqrtf(b1v[cin] + EPSd);
            v = fmaxf(y * inv + (b1b[cin] - b1m[cin] * inv), 0.f);
        }
        h1[col * 64 + cin] = v;
    }
    __syncthreads();
    int c = tid & 63, g = tid >> 6;    // outputs sl = g*8+p (contiguous 8 rows)
    float inv2 = b2g[c] * rsqrtf(b2v[c] + EPSd);
    float sh2  = b2b[c] - b2m[c] * inv2;
    float acc[8];
    #pragma unroll
    for (int p = 0; p < 8; ++p) acc[p] = c2b[c];
    const float4* h14 = (const float4*)h1;   // [col*16 + cin4]
    const float4* wt4 = (const float4*)wtk;  // [(k*16+cin4)*64 + c]
    for (int cin4 = 0; cin4 < 16; ++cin4) {
        float4 xs[10];
        #pragma unroll
        for (int q = 0; q < 10; ++q) xs[q] = h14[(g * 8 + q) * 16 + cin4];
        #pragma unroll
        for (int k = 0; k < 3; ++k) {
            float4 w4 = wt4[(k * 16 + cin4) * 64 + c];
            #pragma unroll
            for (int p = 0; p < 8; ++p) {
                float4 x4 = xs[p + k];
                acc[p] += w4.x * x4.x + w4.y * x4.y + w4.z * x4.z + w4.w * x4.w;
            }
        }
    }
    #pragma unroll
    for (int p = 0; p < 8; ++p) {
        int sl = g * 8 + p;
        float outv = fmaxf(acc[p] * inv2 + sh2, 0.f);
        xf[(b * Sd + s0 + sl) * 64 + c] = outv;
    }
}

// K2: Wh = xf @ gat_W^T + gat_Wb ; s1 = Wh.a1 ; s2 = Wh.a2   (16 nodes/block)
__global__ __launch_bounds__(256) void k2_wh(
        const float* __restrict__ xf,
        const float* __restrict__ gW, const float* __restrict__ gWb,
        const float* __restrict__ a1, const float* __restrict__ a2,
        float* __restrict__ Wh, float* __restrict__ s1, float* __restrict__ s2) {
    __shared__ float4 WT4[1024];   // [kk4*64 + h]
    __shared__ float4 xr4[256];    // [ln*16 + kk4]
    int tid = threadIdx.x;
    int node0 = blockIdx.x * 16;
    for (int fidx = tid; fidx < 1024; fidx += 256) {
        int h_ = fidx >> 4, kk4 = fidx & 15;
        WT4[kk4 * 64 + h_] = ((const float4*)gW)[fidx];
    }
    xr4[tid] = ((const float4*)(xf + node0 * 64))[tid];
    __syncthreads();
    int h = tid & 63, w = tid >> 6;
    float bias = gWb[h];
    float acc0 = bias, acc1 = bias, acc2 = bias, acc3 = bias;
    #pragma unroll
    for (int kk4 = 0; kk4 < 16; ++kk4) {
        float4 w4 = WT4[kk4 * 64 + h];
        float4 xa = xr4[(w * 4 + 0) * 16 + kk4];
        float4 xb = xr4[(w * 4 + 1) * 16 + kk4];
        float4 xc = xr4[(w * 4 + 2) * 16 + kk4];
        float4 xd = xr4[(w * 4 + 3) * 16 + kk4];
        acc0 += w4.x * xa.x + w4.y * xa.y + w4.z * xa.z + w4.w * xa.w;
        acc1 += w4.x * xb.x + w4.y * xb.y + w4.z * xb.z + w4.w * xb.w;
        acc2 += w4.x * xc.x + w4.y * xc.y + w4.z * xc.z + w4.w * xc.w;
        acc3 += w4.x * xd.x + w4.y * xd.y + w4.z * xd.z + w4.w * xd.w;
    }
    float va1 = a1[h], va2 = a2[h];
    float accs[4] = {acc0, acc1, acc2, acc3};
    #pragma unroll
    for (int r = 0; r < 4; ++r) {
        int n = node0 + w * 4 + r;
        Wh[n * 64 + h] = accs[r];
        float r1 = wred_sum(accs[r] * va1);
        float r2 = wred_sum(accs[r] * va2);
        if (h == 0) { s1[n] = r1; s2[n] = r2; }
    }
}

// K4: partial ranks (32 parts of 256 keys) + per-part max (no memset, no atomics)
__global__ __launch_bounds__(256) void k4_rank(const float* __restrict__ s2,
                                               int* __restrict__ rankPart,
                                               float* __restrict__ pmax) {
    __shared__ float4 ts4[64];     // 256 keys
    int bid = blockIdx.x;
    int jg = bid >> 5, part = bid & 31;
    int tid = threadIdx.x;
    if (tid < 64) ts4[tid] = ((const float4*)(s2 + part * 256))[tid];
    __syncthreads();
    if (jg == 0 && tid < 64) {
        float4 t4 = ts4[tid];
        float m = fmaxf(fmaxf(t4.x, t4.y), fmaxf(t4.z, t4.w));
        m = wred_max(m);
        if (tid == 0) pmax[part] = m;
    }
    int j = jg * 256 + tid;
    float tj = s2[j];
    int jloc = j - part * 256;
    int cnt = 0;
    #pragma unroll 4
    for (int q = 0; q < 64; ++q) {
        float4 t4 = ts4[q];
        int rb = q * 4;
        cnt += (t4.x < tj || (t4.x == tj && rb     < jloc)) ? 1 : 0;
        cnt += (t4.y < tj || (t4.y == tj && rb + 1 < jloc)) ? 1 : 0;
        cnt += (t4.z < tj || (t4.z == tj && rb + 2 < jloc)) ? 1 : 0;
        cnt += (t4.w < tj || (t4.w == tj && rb + 3 < jloc)) ? 1 : 0;
    }
    rankPart[part * 8192 + j] = cnt;
}

// K5: sum partial ranks, scatter weighted rows into rank order + tsorted
__global__ __launch_bounds__(256) void k5_scatter(
        const float* __restrict__ Wh, const float* __restrict__ s2,
        const int* __restrict__ rankPart,
        float* __restrict__ Rpos, float* __restrict__ Rneg,
        float* __restrict__ spos, float* __restrict__ sneg,
        float* __restrict__ tsorted) {
    int fidx = blockIdx.x * 256 + threadIdx.x;   // [0, 131072) float4 units
    int j = fidx >> 4, h4 = fidx & 15;
    int r = 0;
    #pragma unroll
    for (int p = 0; p < 32; ++p) r += rankPart[p * 8192 + j];
    float t = s2[j];
    float e1 = expf(t), e2 = expf(0.2f * t);
    float4 wv = ((const float4*)Wh)[fidx];
    ((float4*)Rpos)[r * 16 + h4] = make_float4(e1 * wv.x, e1 * wv.y, e1 * wv.z, e1 * wv.w);
    ((float4*)Rneg)[r * 16 + h4] = make_float4(e2 * wv.x, e2 * wv.y, e2 * wv.z, e2 * wv.w);
    if (h4 == 0) { spos[r] = e1; sneg[r] = e2; tsorted[r] = t; }
}

// K6: per-chunk sums (64 chunks of 128 rows)
__global__ void k6_csum(const float* __restrict__ Rpos, const float* __restrict__ Rneg,
                        const float* __restrict__ spos, const float* __restrict__ sneg,
                        float* __restrict__ csP, float* __restrict__ csN,
                        float* __restrict__ csp, float* __restrict__ csn) {
    int chunk = blockIdx.x, h = threadIdx.x;
    int base = chunk * 128;
    double aP = 0.0, aN = 0.0;
    for (int r = 0; r < 128; ++r) {
        aP += Rpos[(base + r) * 64 + h];
        aN += Rneg[(base + r) * 64 + h];
    }
    csP[chunk * 64 + h] = (float)aP;
    csN[chunk * 64 + h] = (float)aN;
    float sp = spos[base + h] + spos[base + 64 + h];
    float sn = sneg[base + h] + sneg[base + 64 + h];
    sp = wred_sum(sp);
    sn = wred_sum(sn);
    if (h == 0) { csp[chunk] = sp; csn[chunk] = sn; }
}

// K8: expand to full exclusive prefixes (chunk offset computed inline); row Nn = totals
__global__ void k8_expand(const float* __restrict__ Rpos, const float* __restrict__ Rneg,
                          const float* __restrict__ spos, const float* __restrict__ sneg,
                          const float* __restrict__ csP, const float* __restrict__ csN,
                          const float* __restrict__ csp, const float* __restrict__ csn,
                          float* __restrict__ Ppos, float* __restrict__ Pneg,
                          float* __restrict__ ppos, float* __restrict__ pneg) {
    int chunk = blockIdx.x, h = threadIdx.x;
    int base = chunk * 128;
    double runP = 0.0, runN = 0.0;
    for (int ch = 0; ch < chunk; ++ch) { runP += csP[ch * 64 + h]; runN += csN[ch * 64 + h]; }
    for (int r = 0; r < 128; ++r) {
        int idx = base + r;
        Ppos[idx * 64 + h] = (float)runP; runP += Rpos[idx * 64 + h];
        Pneg[idx * 64 + h] = (float)runN; runN += Rneg[idx * 64 + h];
    }
    if (chunk == 63) { Ppos[Nn * 64 + h] = (float)runP; Pneg[Nn * 64 + h] = (float)runN; }
    if (h == 0) {
        double a = 0.0;
        for (int ch = 0; ch < chunk; ++ch) a += csp[ch];
        for (int r = 0; r < 128; ++r) { ppos[base + r] = (float)a; a += spos[base + r]; }
        if (chunk == 63) ppos[Nn] = (float)a;
    }
    if (h == 1) {
        double a = 0.0;
        for (int ch = 0; ch < chunk; ++ch) a += csn[ch];
        for (int r = 0; r < 128; ++r) { pneg[base + r] = (float)a; a += sneg[base + r]; }
        if (chunk == 63) pneg[Nn] = (float)a;
    }
}

// K9a: per-node hp via LDS binary search + split prefix lookups, then time-attn -> h2
__global__ __launch_bounds__(256) void k9a_node(
        const float* __restrict__ s1, const float* __restrict__ tsorted,
        const float* __restrict__ pmax, const float* __restrict__ gab,
        const float* __restrict__ Ppos, const float* __restrict__ Pneg,
        const float* __restrict__ ppos, const float* __restrict__ pneg,
        const float* __restrict__ taW, const float* __restrict__ tab,
        float* __restrict__ h2) {
    __shared__ float4 wt4[1024];   // taW: [kk4*64 + h]
    __shared__ float tso[8192];    // sorted t
    __shared__ float hl[16 * 64];  // hp rows
    int tid = threadIdx.x;
    for (int fidx = tid; fidx < 1024; fidx += 256) {
        int h_ = fidx >> 4, kk4 = fidx & 15;
        wt4[kk4 * 64 + h_] = ((const float4*)taW)[fidx];
    }
    for (int i = tid; i < 2048; i += 256)
        ((float4*)tso)[i] = ((const float4*)tsorted)[i];
    float tmx = pmax[tid & 31];
    tmx = wred_max(tmx);
    __syncthreads();
    int h = tid & 63, w = tid >> 6;
    float gabv = gab[0];
    float tabv = tab[h];
    float Tp  = Ppos[Nn * 64 + h];
    float ppT = ppos[Nn];
    for (int r = 0; r < 4; ++r) {
        int n = blockIdx.x * 16 + w * 4 + r;
        float c = s1[n] + gabv;
        float negc = -c;
        // Shar binary search: k = #{ t <= negc }
        int k = 0;
        #pragma unroll
        for (int stp = 4096; stp > 0; stp >>= 1)
            if (tso[k + stp - 1] <= negc) k += stp;
        if (k == 8191 && tso[8191] <= negc) k = 8192;
        float z = c + tmx;
        float m = (z >= 0.f) ? z : 0.2f * z;     // max_j e_ij
        float E1 = expf(c - m), E2 = expf(0.2f * c - m);
        float Pp = Ppos[k * 64 + h], Pn = Pneg[k * 64 + h];
        float num = E1 * (Tp - Pp) + E2 * Pn;
        float den = E1 * (ppT - ppos[k]) + E2 * pneg[k];
        float hp = num / den;
        int slot = w * 4 + r;
        hl[slot * 64 + h] = hp;
        float v = tabv;
        const float4* hlr = (const float4*)&hl[slot * 64];
        #pragma unroll
        for (int kk4 = 0; kk4 < 16; ++kk4) {
            float4 w4 = wt4[kk4 * 64 + h];
            float4 x4 = hlr[kk4];
            v += w4.x * x4.x + w4.y * x4.y + w4.z * x4.z + w4.w * x4.w;
        }
        float mx = wred_max(v);
        float e = expf(v - mx);
        float se = wred_sum(e);
        h2[n * 64 + h] = hp * (e / se);
    }
}

// K9b: mean over S + MLP head -> out
__global__ __launch_bounds__(256) void k9b_pool(
        const float* __restrict__ h2,
        const float* __restrict__ p1W, const float* __restrict__ p1b,
        const float* __restrict__ p2W, const float* __restrict__ p2b,
        float* __restrict__ out) {
    __shared__ float pacc[4 * 64];
    __shared__ float pl[64];
    __shared__ float p1s[32 * 65];
    int tid = threadIdx.x, b = blockIdx.x;
    int w = tid >> 6, h = tid & 63;
    for (int idx = tid; idx < 2048; idx += 256) {
        int q = idx >> 6, kk = idx & 63;
        p1s[q * 65 + kk] = p1W[idx];
    }
    float a = 0.f;
    for (int s = w * 32; s < w * 32 + 32; ++s) a += h2[(b * Sd + s) * 64 + h];
    pacc[w * 64 + h] = a;
    __syncthreads();
    if (w == 0) {
        float pooled = (pacc[h] + pacc[64 + h] + pacc[128 + h] + pacc[192 + h]) * (1.f / 128.f);
        pl[h] = pooled;
        float val = 0.f;
        if (h < 32) {
            float acc = p1b[h];
            #pragma unroll
            for (int kk = 0; kk < 64; ++kk) acc += p1s[h * 65 + kk] * pl[kk];
            val = p2W[h] * fmaxf(acc, 0.f);
        }
        val = wred_sum(val);
        if (h == 0) out[b] = val + p2b[0];
    }
}

extern "C" void kernel_launch(void* const* d_in, const int* in_sizes, int n_in,
                              void* d_out, int out_size, void* d_ws, size_t ws_size,
                              hipStream_t stream) {
    const float* x    = (const float*)d_in[0];
    const float* c1w  = (const float*)d_in[1];
    const float* c1b  = (const float*)d_in[2];
    const float* b1g  = (const float*)d_in[3];
    const float* b1b  = (const float*)d_in[4];
    const float* b1m  = (const float*)d_in[5];
    const float* b1v  = (const float*)d_in[6];
    const float* c2w  = (const float*)d_in[7];
    const float* c2b  = (const float*)d_in[8];
    const float* b2g  = (const float*)d_in[9];
    const float* b2b  = (const float*)d_in[10];
    const float* b2m  = (const float*)d_in[11];
    const float* b2v  = (const float*)d_in[12];
    const float* gW   = (const float*)d_in[13];
    const float* gWb  = (const float*)d_in[14];
    const float* ga1  = (const float*)d_in[15];
    const float* ga2  = (const float*)d_in[16];
    const float* gab  = (const float*)d_in[17];
    const float* taW  = (const float*)d_in[18];
    const float* tab  = (const float*)d_in[19];
    const float* p1W  = (const float*)d_in[20];
    const float* p1b  = (const float*)d_in[21];
    const float* p2W  = (const float*)d_in[22];
    const float* p2b  = (const float*)d_in[23];
    float* out = (float*)d_out;

    float* ws = (float*)d_ws;
    float* xf      = ws;                    // 524288
    float* Wh      = xf + 524288;           // 524288
    float* s1      = Wh + 524288;           // 8192
    float* s2v     = s1 + 8192;             // 8192
    float* tsorted = s2v + 8192;            // 8192
    float* spos    = tsorted + 8192;        // 8192
    float* sneg    = spos + 8192;           // 8192
    float* ppos    = sneg + 8192;           // 8256 (8193 used)
    float* pneg    = ppos + 8256;           // 8256
    float* csP     = pneg + 8256;           // 4096
    float* csN     = csP + 4096;            // 4096
    float* csp     = csN + 4096;            // 64
    float* csn     = csp + 64;              // 64
    float* pmax    = csn + 64;              // 64 (32 used)
    int*   rankPart= (int*)(pmax + 64);     // 32*8192 ints = 262144
    float* Rpos    = (float*)(rankPart + 262144);  // 524288
    float* Rneg    = Rpos + 524288;         // 524288
    float* Ppos    = Rneg + 524288;         // 524352 (8193 rows)
    float* Pneg    = Ppos + 524352;         // 524352
    float* h2      = Rpos;                  // alias: Rpos dead after K8

    k1_features<<<256, 256, 0, stream>>>(x, c1w, c1b, b1g, b1b, b1m, b1v,
                                         c2w, c2b, b2g, b2b, b2m, b2v, xf);
    k2_wh<<<512, 256, 0, stream>>>(xf, gW, gWb, ga1, ga2, Wh, s1, s2v);
    k4_rank<<<1024, 256, 0, stream>>>(s2v, rankPart, pmax);
    k5_scatter<<<512, 256, 0, stream>>>(Wh, s2v, rankPart, Rpos, Rneg, spos, sneg, tsorted);
    k6_csum<<<64, 64, 0, stream>>>(Rpos, Rneg, spos, sneg, csP, csN, csp, csn);
    k8_expand<<<64, 64, 0, stream>>>(Rpos, Rneg, spos, sneg, csP, csN, csp, csn,
                                     Ppos, Pneg, ppos, pneg);
    k9a_node<<<512, 256, 0, stream>>>(s1, tsorted, pmax, gab, Ppos, Pneg, ppos, pneg,
                                      taW, tab, h2);
    k9b_pool<<<64, 256, 0, stream>>>(h2, p1W, p1b, p2W, p2b, out);
}

// Round 3
// 69.520 us; speedup vs baseline: 2.2615x; 1.3927x over previous
//
#include <hip/hip_runtime.h>
#include <hip/hip_bf16.h>

#define Hd 64
#define Sd 128
#define Bd 64
#define Nn 8192
#define EPSd 1e-5f

__device__ __forceinline__ float wred_sum(float v) {
    for (int m = 32; m; m >>= 1) v += __shfl_xor(v, m);
    return v;
}
__device__ __forceinline__ float wred_max(float v) {
    for (int m = 32; m; m >>= 1) v = fmaxf(v, __shfl_xor(v, m));
    return v;
}
// 64-lane inclusive scan
__device__ __forceinline__ float wscan_incl(float x, int lane) {
    #pragma unroll
    for (int d = 1; d < 64; d <<= 1) {
        float t = __shfl_up(x, d);
        if (lane >= d) x += t;
    }
    return x;
}

// K1: conv1+bn1+relu -> conv2+bn2+relu -> xf [N][64]
__global__ __launch_bounds__(256) void k1_features(
        const float* __restrict__ x,
        const float* __restrict__ c1w, const float* __restrict__ c1b,
        const float* __restrict__ b1g, const float* __restrict__ b1b,
        const float* __restrict__ b1m, const float* __restrict__ b1v,
        const float* __restrict__ c2w, const float* __restrict__ c2b,
        const float* __restrict__ b2g, const float* __restrict__ b2b,
        const float* __restrict__ b2m, const float* __restrict__ b2v,
        float* __restrict__ xf) {
    __shared__ float h1[34 * 64];      // [col][cin]
    __shared__ float wtk[3 * 16 * 64 * 4];  // float4 view: [(k*16+cin4)*64 + c]
    int b  = blockIdx.x >> 2;
    int s0 = (blockIdx.x & 3) * 32;
    int tid = threadIdx.x;
    for (int idx = tid; idx < 12288; idx += 256) {
        int j    = idx & 3;
        int c    = (idx >> 2) & 63;
        int cin4 = (idx >> 8) & 15;
        int k    = idx >> 12;
        wtk[idx] = c2w[(c * 64 + cin4 * 4 + j) * 3 + k];
    }
    for (int idx = tid; idx < 34 * 64; idx += 256) {
        int cin = idx & 63;
        int col = idx >> 6;
        int s   = s0 - 1 + col;
        float v = 0.f;
        if (s >= 0 && s < Sd) {
            float xm = (s > 0)      ? x[b * Sd + s - 1] : 0.f;
            float x0 = x[b * Sd + s];
            float xp = (s < Sd - 1) ? x[b * Sd + s + 1] : 0.f;
            float y  = c1w[cin * 3 + 0] * xm + c1w[cin * 3 + 1] * x0 + c1w[cin * 3 + 2] * xp + c1b[cin];
            float inv = b1g[cin] * rsqrtf(b1v[cin] + EPSd);
            v = fmaxf(y * inv + (b1b[cin] - b1m[cin] * inv), 0.f);
        }
        h1[col * 64 + cin] = v;
    }
    __syncthreads();
    int c = tid & 63, g = tid >> 6;
    float inv2 = b2g[c] * rsqrtf(b2v[c] + EPSd);
    float sh2  = b2b[c] - b2m[c] * inv2;
    float acc[8];
    #pragma unroll
    for (int p = 0; p < 8; ++p) acc[p] = c2b[c];
    const float4* h14 = (const float4*)h1;
    const float4* wt4 = (const float4*)wtk;
    for (int cin4 = 0; cin4 < 16; ++cin4) {
        float4 xs[10];
        #pragma unroll
        for (int q = 0; q < 10; ++q) xs[q] = h14[(g * 8 + q) * 16 + cin4];
        #pragma unroll
        for (int k = 0; k < 3; ++k) {
            float4 w4 = wt4[(k * 16 + cin4) * 64 + c];
            #pragma unroll
            for (int p = 0; p < 8; ++p) {
                float4 x4 = xs[p + k];
                acc[p] += w4.x * x4.x + w4.y * x4.y + w4.z * x4.z + w4.w * x4.w;
            }
        }
    }
    #pragma unroll
    for (int p = 0; p < 8; ++p) {
        int sl = g * 8 + p;
        float outv = fmaxf(acc[p] * inv2 + sh2, 0.f);
        xf[(b * Sd + s0 + sl) * 64 + c] = outv;
    }
}

// K2: Wh = xf @ gat_W^T + gat_Wb ; s1 = Wh.a1 ; s2 = Wh.a2   (16 nodes/block)
__global__ __launch_bounds__(256) void k2_wh(
        const float* __restrict__ xf,
        const float* __restrict__ gW, const float* __restrict__ gWb,
        const float* __restrict__ a1, const float* __restrict__ a2,
        float* __restrict__ Wh, float* __restrict__ s1, float* __restrict__ s2) {
    __shared__ float4 WT4[1024];   // [kk4*64 + h]
    __shared__ float4 xr4[256];    // [ln*16 + kk4]
    int tid = threadIdx.x;
    int node0 = blockIdx.x * 16;
    for (int fidx = tid; fidx < 1024; fidx += 256) {
        int h_ = fidx >> 4, kk4 = fidx & 15;
        WT4[kk4 * 64 + h_] = ((const float4*)gW)[fidx];
    }
    xr4[tid] = ((const float4*)(xf + node0 * 64))[tid];
    __syncthreads();
    int h = tid & 63, w = tid >> 6;
    float bias = gWb[h];
    float acc0 = bias, acc1 = bias, acc2 = bias, acc3 = bias;
    #pragma unroll
    for (int kk4 = 0; kk4 < 16; ++kk4) {
        float4 w4 = WT4[kk4 * 64 + h];
        float4 xa = xr4[(w * 4 + 0) * 16 + kk4];
        float4 xb = xr4[(w * 4 + 1) * 16 + kk4];
        float4 xc = xr4[(w * 4 + 2) * 16 + kk4];
        float4 xd = xr4[(w * 4 + 3) * 16 + kk4];
        acc0 += w4.x * xa.x + w4.y * xa.y + w4.z * xa.z + w4.w * xa.w;
        acc1 += w4.x * xb.x + w4.y * xb.y + w4.z * xb.z + w4.w * xb.w;
        acc2 += w4.x * xc.x + w4.y * xc.y + w4.z * xc.z + w4.w * xc.w;
        acc3 += w4.x * xd.x + w4.y * xd.y + w4.z * xd.z + w4.w * xd.w;
    }
    float va1 = a1[h], va2 = a2[h];
    float accs[4] = {acc0, acc1, acc2, acc3};
    #pragma unroll
    for (int r = 0; r < 4; ++r) {
        int n = node0 + w * 4 + r;
        Wh[n * 64 + h] = accs[r];
        float r1 = wred_sum(accs[r] * va1);
        float r2 = wred_sum(accs[r] * va2);
        if (h == 0) { s1[n] = r1; s2[n] = r2; }
    }
}

// K4: partial ranks (32 parts of 256 keys) + per-part max
__global__ __launch_bounds__(256) void k4_rank(const float* __restrict__ s2,
                                               int* __restrict__ rankPart,
                                               float* __restrict__ pmax) {
    __shared__ float4 ts4[64];
    int bid = blockIdx.x;
    int jg = bid >> 5, part = bid & 31;
    int tid = threadIdx.x;
    if (tid < 64) ts4[tid] = ((const float4*)(s2 + part * 256))[tid];
    __syncthreads();
    if (jg == 0 && tid < 64) {
        float4 t4 = ts4[tid];
        float m = fmaxf(fmaxf(t4.x, t4.y), fmaxf(t4.z, t4.w));
        m = wred_max(m);
        if (tid == 0) pmax[part] = m;
    }
    int j = jg * 256 + tid;
    float tj = s2[j];
    int jloc = j - part * 256;
    int cnt = 0;
    #pragma unroll 4
    for (int q = 0; q < 64; ++q) {
        float4 t4 = ts4[q];
        int rb = q * 4;
        cnt += (t4.x < tj || (t4.x == tj && rb     < jloc)) ? 1 : 0;
        cnt += (t4.y < tj || (t4.y == tj && rb + 1 < jloc)) ? 1 : 0;
        cnt += (t4.z < tj || (t4.z == tj && rb + 2 < jloc)) ? 1 : 0;
        cnt += (t4.w < tj || (t4.w == tj && rb + 3 < jloc)) ? 1 : 0;
    }
    rankPart[part * 8192 + j] = cnt;
}

// K5: sum partial ranks, scatter weighted rows into rank order + tsorted
__global__ __launch_bounds__(256) void k5_scatter(
        const float* __restrict__ Wh, const float* __restrict__ s2,
        const int* __restrict__ rankPart,
        float* __restrict__ Rpos, float* __restrict__ Rneg,
        float* __restrict__ spos, float* __restrict__ sneg,
        float* __restrict__ tsorted) {
    int fidx = blockIdx.x * 256 + threadIdx.x;
    int j = fidx >> 4, h4 = fidx & 15;
    int r = 0;
    #pragma unroll
    for (int p = 0; p < 32; ++p) r += rankPart[p * 8192 + j];
    float t = s2[j];
    float e1 = expf(t), e2 = expf(0.2f * t);
    float4 wv = ((const float4*)Wh)[fidx];
    ((float4*)Rpos)[r * 16 + h4] = make_float4(e1 * wv.x, e1 * wv.y, e1 * wv.z, e1 * wv.w);
    ((float4*)Rneg)[r * 16 + h4] = make_float4(e2 * wv.x, e2 * wv.y, e2 * wv.z, e2 * wv.w);
    if (h4 == 0) { spos[r] = e1; sneg[r] = e2; tsorted[r] = t; }
}

// K6: per-chunk sums — 256 threads/block, 4 waves × 32 register rows
__global__ __launch_bounds__(256) void k6_csum(
        const float* __restrict__ Rpos, const float* __restrict__ Rneg,
        const float* __restrict__ spos, const float* __restrict__ sneg,
        float* __restrict__ csP, float* __restrict__ csN,
        float* __restrict__ csp, float* __restrict__ csn) {
    __shared__ float ldsP[4][64], ldsN[4][64];
    int ch = blockIdx.x, tid = threadIdx.x;
    int h = tid & 63, w = tid >> 6;
    int rb = ch * 128 + w * 32;
    double aP = 0.0, aN = 0.0;
    #pragma unroll
    for (int r = 0; r < 32; ++r) {
        aP += Rpos[(rb + r) * 64 + h];
        aN += Rneg[(rb + r) * 64 + h];
    }
    ldsP[w][h] = (float)aP; ldsN[w][h] = (float)aN;
    __syncthreads();
    if (w == 0) {
        csP[ch * 64 + h] = ldsP[0][h] + ldsP[1][h] + ldsP[2][h] + ldsP[3][h];
    } else if (w == 1) {
        csN[ch * 64 + h] = ldsN[0][h] + ldsN[1][h] + ldsN[2][h] + ldsN[3][h];
    } else if (w == 2) {
        float v = spos[ch * 128 + h] + spos[ch * 128 + 64 + h];
        v = wred_sum(v);
        if (h == 0) csp[ch] = v;
    } else {
        float v = sneg[ch * 128 + h] + sneg[ch * 128 + 64 + h];
        v = wred_sum(v);
        if (h == 0) csn[ch] = v;
    }
}

// K8: expand to full exclusive prefixes — 256 threads/block, register-batched
__global__ __launch_bounds__(256) void k8_expand(
        const float* __restrict__ Rpos, const float* __restrict__ Rneg,
        const float* __restrict__ spos, const float* __restrict__ sneg,
        const float* __restrict__ csP, const float* __restrict__ csN,
        const float* __restrict__ csp, const float* __restrict__ csn,
        float* __restrict__ Ppos, float* __restrict__ Pneg,
        float* __restrict__ ppos, float* __restrict__ pneg) {
    __shared__ float ldsA[4][64], ldsB[4][64];
    __shared__ float cbPs[64], cbNs[64];
    int ch = blockIdx.x, tid = threadIdx.x;
    int h = tid & 63, w = tid >> 6;
    // chunk base per column (wave-strided partial sums of prior chunk sums)
    double bp = 0.0, bn = 0.0;
    for (int p = w; p < ch; p += 4) { bp += csP[p * 64 + h]; bn += csN[p * 64 + h]; }
    ldsA[w][h] = (float)bp; ldsB[w][h] = (float)bn;
    __syncthreads();
    if (w == 0) {
        cbPs[h] = ldsA[0][h] + ldsA[1][h] + ldsA[2][h] + ldsA[3][h];
        cbNs[h] = ldsB[0][h] + ldsB[1][h] + ldsB[2][h] + ldsB[3][h];
    }
    __syncthreads();
    float cbP = cbPs[h], cbN = cbNs[h];
    int rb = ch * 128 + w * 32;
    float v[32];
    // ---- pass 1: Rpos -> Ppos ----
    #pragma unroll
    for (int r = 0; r < 32; ++r) v[r] = Rpos[(rb + r) * 64 + h];
    double acc = 0.0;
    #pragma unroll
    for (int r = 0; r < 32; ++r) acc += v[r];
    ldsA[w][h] = (float)acc;
    __syncthreads();
    float off = cbP;
    #pragma unroll
    for (int w2 = 0; w2 < 4; ++w2) if (w2 < w) off += ldsA[w2][h];
    double a2_ = 0.0;
    #pragma unroll
    for (int r = 0; r < 32; ++r) { Ppos[(rb + r) * 64 + h] = off + (float)a2_; a2_ += v[r]; }
    if (ch == 63 && w == 3) Ppos[Nn * 64 + h] = off + (float)a2_;
    __syncthreads();
    // ---- pass 2: Rneg -> Pneg ----
    #pragma unroll
    for (int r = 0; r < 32; ++r) v[r] = Rneg[(rb + r) * 64 + h];
    acc = 0.0;
    #pragma unroll
    for (int r = 0; r < 32; ++r) acc += v[r];
    ldsB[w][h] = (float)acc;
    __syncthreads();
    off = cbN;
    #pragma unroll
    for (int w2 = 0; w2 < 4; ++w2) if (w2 < w) off += ldsB[w2][h];
    a2_ = 0.0;
    #pragma unroll
    for (int r = 0; r < 32; ++r) { Pneg[(rb + r) * 64 + h] = off + (float)a2_; a2_ += v[r]; }
    if (ch == 63 && w == 3) Pneg[Nn * 64 + h] = off + (float)a2_;
    // ---- scalar prefixes: wave0 -> ppos, wave1 -> pneg ----
    if (w == 0) {
        int lane = h;
        float bs = (lane < ch) ? csp[lane] : 0.f;
        bs = wred_sum(bs);
        float v0 = spos[ch * 128 + lane], v1 = spos[ch * 128 + 64 + lane];
        float i0 = wscan_incl(v0, lane);
        float t0 = __shfl(i0, 63);
        float i1 = wscan_incl(v1, lane);
        ppos[ch * 128 + lane]      = bs + i0 - v0;
        ppos[ch * 128 + 64 + lane] = bs + t0 + i1 - v1;
        if (ch == 63 && lane == 63) ppos[Nn] = bs + t0 + i1;
    } else if (w == 1) {
        int lane = h;
        float bs = (lane < ch) ? csn[lane] : 0.f;
        bs = wred_sum(bs);
        float v0 = sneg[ch * 128 + lane], v1 = sneg[ch * 128 + 64 + lane];
        float i0 = wscan_incl(v0, lane);
        float t0 = __shfl(i0, 63);
        float i1 = wscan_incl(v1, lane);
        pneg[ch * 128 + lane]      = bs + i0 - v0;
        pneg[ch * 128 + 64 + lane] = bs + t0 + i1 - v1;
        if (ch == 63 && lane == 63) pneg[Nn] = bs + t0 + i1;
    }
}

// K9a: per-node hp via LDS binary search + split prefix lookups, then time-attn -> h2
__global__ __launch_bounds__(256) void k9a_node(
        const float* __restrict__ s1, const float* __restrict__ tsorted,
        const float* __restrict__ pmax, const float* __restrict__ gab,
        const float* __restrict__ Ppos, const float* __restrict__ Pneg,
        const float* __restrict__ ppos, const float* __restrict__ pneg,
        const float* __restrict__ taW, const float* __restrict__ tab,
        float* __restrict__ h2) {
    __shared__ float4 wt4[1024];   // taW: [kk4*64 + h]
    __shared__ float tso[8192];    // sorted t
    __shared__ float hl[16 * 64];  // hp rows
    int tid = threadIdx.x;
    for (int fidx = tid; fidx < 1024; fidx += 256) {
        int h_ = fidx >> 4, kk4 = fidx & 15;
        wt4[kk4 * 64 + h_] = ((const float4*)taW)[fidx];
    }
    for (int i = tid; i < 2048; i += 256)
        ((float4*)tso)[i] = ((const float4*)tsorted)[i];
    float tmx = pmax[tid & 31];
    tmx = wred_max(tmx);
    __syncthreads();
    int h = tid & 63, w = tid >> 6;
    float gabv = gab[0];
    float tabv = tab[h];
    float Tp  = Ppos[Nn * 64 + h];
    float ppT = ppos[Nn];
    for (int r = 0; r < 4; ++r) {
        int n = blockIdx.x * 16 + w * 4 + r;
        float c = s1[n] + gabv;
        float negc = -c;
        int k = 0;
        #pragma unroll
        for (int stp = 4096; stp > 0; stp >>= 1)
            if (tso[k + stp - 1] <= negc) k += stp;
        if (k == 8191 && tso[8191] <= negc) k = 8192;
        float z = c + tmx;
        float m = (z >= 0.f) ? z : 0.2f * z;
        float E1 = expf(c - m), E2 = expf(0.2f * c - m);
        float Pp = Ppos[k * 64 + h], Pn = Pneg[k * 64 + h];
        float num = E1 * (Tp - Pp) + E2 * Pn;
        float den = E1 * (ppT - ppos[k]) + E2 * pneg[k];
        float hp = num / den;
        int slot = w * 4 + r;
        hl[slot * 64 + h] = hp;
        float vv = tabv;
        const float4* hlr = (const float4*)&hl[slot * 64];
        #pragma unroll
        for (int kk4 = 0; kk4 < 16; ++kk4) {
            float4 w4 = wt4[kk4 * 64 + h];
            float4 x4 = hlr[kk4];
            vv += w4.x * x4.x + w4.y * x4.y + w4.z * x4.z + w4.w * x4.w;
        }
        float mx = wred_max(vv);
        float e = expf(vv - mx);
        float se = wred_sum(e);
        h2[n * 64 + h] = hp * (e / se);
    }
}

// K9b: mean over S + MLP head -> out
__global__ __launch_bounds__(256) void k9b_pool(
        const float* __restrict__ h2,
        const float* __restrict__ p1W, const float* __restrict__ p1b,
        const float* __restrict__ p2W, const float* __restrict__ p2b,
        float* __restrict__ out) {
    __shared__ float pacc[4 * 64];
    __shared__ float pl[64];
    __shared__ float p1s[32 * 65];
    int tid = threadIdx.x, b = blockIdx.x;
    int w = tid >> 6, h = tid & 63;
    for (int idx = tid; idx < 2048; idx += 256) {
        int q = idx >> 6, kk = idx & 63;
        p1s[q * 65 + kk] = p1W[idx];
    }
    float a = 0.f;
    for (int s = w * 32; s < w * 32 + 32; ++s) a += h2[(b * Sd + s) * 64 + h];
    pacc[w * 64 + h] = a;
    __syncthreads();
    if (w == 0) {
        float pooled = (pacc[h] + pacc[64 + h] + pacc[128 + h] + pacc[192 + h]) * (1.f / 128.f);
        pl[h] = pooled;
        float val = 0.f;
        if (h < 32) {
            float acc = p1b[h];
            #pragma unroll
            for (int kk = 0; kk < 64; ++kk) acc += p1s[h * 65 + kk] * pl[kk];
            val = p2W[h] * fmaxf(acc, 0.f);
        }
        val = wred_sum(val);
        if (h == 0) out[b] = val + p2b[0];
    }
}

extern "C" void kernel_launch(void* const* d_in, const int* in_sizes, int n_in,
                              void* d_out, int out_size, void* d_ws, size_t ws_size,
                              hipStream_t stream) {
    const float* x    = (const float*)d_in[0];
    const float* c1w  = (const float*)d_in[1];
    const float* c1b  = (const float*)d_in[2];
    const float* b1g  = (const float*)d_in[3];
    const float* b1b  = (const float*)d_in[4];
    const float* b1m  = (const float*)d_in[5];
    const float* b1v  = (const float*)d_in[6];
    const float* c2w  = (const float*)d_in[7];
    const float* c2b  = (const float*)d_in[8];
    const float* b2g  = (const float*)d_in[9];
    const float* b2b  = (const float*)d_in[10];
    const float* b2m  = (const float*)d_in[11];
    const float* b2v  = (const float*)d_in[12];
    const float* gW   = (const float*)d_in[13];
    const float* gWb  = (const float*)d_in[14];
    const float* ga1  = (const float*)d_in[15];
    const float* ga2  = (const float*)d_in[16];
    const float* gab  = (const float*)d_in[17];
    const float* taW  = (const float*)d_in[18];
    const float* tab  = (const float*)d_in[19];
    const float* p1W  = (const float*)d_in[20];
    const float* p1b  = (const float*)d_in[21];
    const float* p2W  = (const float*)d_in[22];
    const float* p2b  = (const float*)d_in[23];
    float* out = (float*)d_out;

    float* ws = (float*)d_ws;
    float* xf      = ws;                    // 524288
    float* Wh      = xf + 524288;           // 524288
    float* s1      = Wh + 524288;           // 8192
    float* s2v     = s1 + 8192;             // 8192
    float* tsorted = s2v + 8192;            // 8192
    float* spos    = tsorted + 8192;        // 8192
    float* sneg    = spos + 8192;           // 8192
    float* ppos    = sneg + 8192;           // 8256 (8193 used)
    float* pneg    = ppos + 8256;           // 8256
    float* csP     = pneg + 8256;           // 4096
    float* csN     = csP + 4096;            // 4096
    float* csp     = csN + 4096;            // 64
    float* csn     = csp + 64;              // 64
    float* pmax    = csn + 64;              // 64 (32 used)
    int*   rankPart= (int*)(pmax + 64);     // 32*8192 ints
    float* Rpos    = (float*)(rankPart + 262144);  // 524288
    float* Rneg    = Rpos + 524288;         // 524288
    float* Ppos    = Rneg + 524288;         // 524352 (8193 rows)
    float* Pneg    = Ppos + 524352;         // 524352
    float* h2      = Rpos;                  // alias: Rpos dead after K8

    k1_features<<<256, 256, 0, stream>>>(x, c1w, c1b, b1g, b1b, b1m, b1v,
                                         c2w, c2b, b2g, b2b, b2m, b2v, xf);
    k2_wh<<<512, 256, 0, stream>>>(xf, gW, gWb, ga1, ga2, Wh, s1, s2v);
    k4_rank<<<1024, 256, 0, stream>>>(s2v, rankPart, pmax);
    k5_scatter<<<512, 256, 0, stream>>>(Wh, s2v, rankPart, Rpos, Rneg, spos, sneg, tsorted);
    k6_csum<<<64, 256, 0, stream>>>(Rpos, Rneg, spos, sneg, csP, csN, csp, csn);
    k8_expand<<<64, 256, 0, stream>>>(Rpos, Rneg, spos, sneg, csP, csN, csp, csn,
                                      Ppos, Pneg, ppos, pneg);
    k9a_node<<<512, 256, 0, stream>>>(s1, tsorted, pmax, gab, Ppos, Pneg, ppos, pneg,
                                      taW, tab, h2);
    k9b_pool<<<64, 256, 0, stream>>>(h2, p1W, p1b, p2W, p2b, out);
}

// Round 4
// 68.567 us; speedup vs baseline: 2.2929x; 1.0139x over previous
//
#include <hip/hip_runtime.h>
#include <hip/hip_bf16.h>

#define Hd 64
#define Sd 128
#define Bd 64
#define Nn 8192
#define EPSd 1e-5f

__device__ __forceinline__ float wred_sum(float v) {
    for (int m = 32; m; m >>= 1) v += __shfl_xor(v, m);
    return v;
}
__device__ __forceinline__ float wred_max(float v) {
    for (int m = 32; m; m >>= 1) v = fmaxf(v, __shfl_xor(v, m));
    return v;
}
// 64-lane inclusive scan
__device__ __forceinline__ float wscan_incl(float x, int lane) {
    #pragma unroll
    for (int d = 1; d < 64; d <<= 1) {
        float t = __shfl_up(x, d);
        if (lane >= d) x += t;
    }
    return x;
}

// A: conv1+bn1+relu -> conv2+bn2+relu -> (in LDS) -> Wh, s1, s2  (32 nodes/block)
__global__ __launch_bounds__(256) void kA_feat_wh(
        const float* __restrict__ x,
        const float* __restrict__ c1w, const float* __restrict__ c1b,
        const float* __restrict__ b1g, const float* __restrict__ b1b,
        const float* __restrict__ b1m, const float* __restrict__ b1v,
        const float* __restrict__ c2w, const float* __restrict__ c2b,
        const float* __restrict__ b2g, const float* __restrict__ b2b,
        const float* __restrict__ b2m, const float* __restrict__ b2v,
        const float* __restrict__ gW, const float* __restrict__ gWb,
        const float* __restrict__ a1, const float* __restrict__ a2,
        float* __restrict__ Wh, float* __restrict__ s1, float* __restrict__ s2) {
    __shared__ float buf[14464];           // phase1: h1[0..2176) | wtk[2176..14464)
    float* h1  = buf;                      // [col][cin], 34*64
    float* wtk = buf + 2176;               // [(k*16+cin4)*256 + c*4 + j]
    int b  = blockIdx.x >> 2;
    int s0 = (blockIdx.x & 3) * 32;
    int tid = threadIdx.x;
    for (int idx = tid; idx < 12288; idx += 256) {
        int j    = idx & 3;
        int c    = (idx >> 2) & 63;
        int cin4 = (idx >> 8) & 15;
        int k    = idx >> 12;
        wtk[idx] = c2w[(c * 64 + cin4 * 4 + j) * 3 + k];
    }
    for (int idx = tid; idx < 34 * 64; idx += 256) {
        int cin = idx & 63;
        int col = idx >> 6;
        int s   = s0 - 1 + col;
        float v = 0.f;
        if (s >= 0 && s < Sd) {
            float xm = (s > 0)      ? x[b * Sd + s - 1] : 0.f;
            float x0 = x[b * Sd + s];
            float xp = (s < Sd - 1) ? x[b * Sd + s + 1] : 0.f;
            float y  = c1w[cin * 3 + 0] * xm + c1w[cin * 3 + 1] * x0 + c1w[cin * 3 + 2] * xp + c1b[cin];
            float inv = b1g[cin] * rsqrtf(b1v[cin] + EPSd);
            v = fmaxf(y * inv + (b1b[cin] - b1m[cin] * inv), 0.f);
        }
        h1[col * 64 + cin] = v;
    }
    __syncthreads();
    int c = tid & 63, g = tid >> 6;
    float inv2 = b2g[c] * rsqrtf(b2v[c] + EPSd);
    float sh2  = b2b[c] - b2m[c] * inv2;
    float acc[8];
    #pragma unroll
    for (int p = 0; p < 8; ++p) acc[p] = c2b[c];
    {
        const float4* h14 = (const float4*)h1;
        const float4* wt4 = (const float4*)wtk;
        for (int cin4 = 0; cin4 < 16; ++cin4) {
            float4 xs[10];
            #pragma unroll
            for (int q = 0; q < 10; ++q) xs[q] = h14[(g * 8 + q) * 16 + cin4];
            #pragma unroll
            for (int k = 0; k < 3; ++k) {
                float4 w4 = wt4[(k * 16 + cin4) * 64 + c];
                #pragma unroll
                for (int p = 0; p < 8; ++p) {
                    float4 x4 = xs[p + k];
                    acc[p] += w4.x * x4.x + w4.y * x4.y + w4.z * x4.z + w4.w * x4.w;
                }
            }
        }
    }
    __syncthreads();   // all conv reads of h1/wtk done; safe to overwrite
    // phase2 aliasing: xfl over h1 region, gWT4 over wtk region
    float*  xfl  = buf;                    // [sl][c], 32*64
    float4* gWT4 = (float4*)(buf + 2176);  // [kk4*64 + h]
    #pragma unroll
    for (int p = 0; p < 8; ++p)
        xfl[(g * 8 + p) * 64 + c] = fmaxf(acc[p] * inv2 + sh2, 0.f);
    for (int fidx = tid; fidx < 1024; fidx += 256) {
        int h_ = fidx >> 4, kk4 = fidx & 15;
        gWT4[kk4 * 64 + h_] = ((const float4*)gW)[fidx];
    }
    __syncthreads();
    int h = tid & 63, w = tid >> 6;
    float4 wreg[16];
    #pragma unroll
    for (int kk4 = 0; kk4 < 16; ++kk4) wreg[kk4] = gWT4[kk4 * 64 + h];
    float va1 = a1[h], va2 = a2[h], bias = gWb[h];
    const float4* xf4 = (const float4*)xfl;
    int n0 = b * Sd + s0;
    for (int q = 0; q < 8; ++q) {
        int sl = w * 8 + q;
        float accw = bias;
        #pragma unroll
        for (int kk4 = 0; kk4 < 16; ++kk4) {
            float4 x4 = xf4[sl * 16 + kk4];
            accw += wreg[kk4].x * x4.x + wreg[kk4].y * x4.y + wreg[kk4].z * x4.z + wreg[kk4].w * x4.w;
        }
        int n = n0 + sl;
        Wh[n * 64 + h] = accw;
        float r1 = wred_sum(accw * va1);
        float r2 = wred_sum(accw * va2);
        if (h == 0) { s1[n] = r1; s2[n] = r2; }
    }
}

// B: partial ranks AND partial k-counts (32 parts of 256 keys) + per-part max
__global__ __launch_bounds__(256) void kB_rank(
        const float* __restrict__ s2, const float* __restrict__ s1,
        const float* __restrict__ gab,
        int* __restrict__ rankPart, int* __restrict__ kPart,
        float* __restrict__ pmax) {
    __shared__ float4 ts4[64];
    int bid = blockIdx.x;
    int jg = bid >> 5, part = bid & 31;
    int tid = threadIdx.x;
    if (tid < 64) ts4[tid] = ((const float4*)(s2 + part * 256))[tid];
    __syncthreads();
    if (jg == 0 && tid < 64) {
        float4 t4 = ts4[tid];
        float m = fmaxf(fmaxf(t4.x, t4.y), fmaxf(t4.z, t4.w));
        m = wred_max(m);
        if (tid == 0) pmax[part] = m;
    }
    int j = jg * 256 + tid;
    float tj = s2[j];
    float negc = -(s1[j] + gab[0]);
    int jloc = j - part * 256;
    int cntR = 0, cntK = 0;
    #pragma unroll 4
    for (int q = 0; q < 64; ++q) {
        float4 t4 = ts4[q];
        int rb = q * 4;
        cntR += (t4.x < tj || (t4.x == tj && rb     < jloc)) ? 1 : 0;
        cntR += (t4.y < tj || (t4.y == tj && rb + 1 < jloc)) ? 1 : 0;
        cntR += (t4.z < tj || (t4.z == tj && rb + 2 < jloc)) ? 1 : 0;
        cntR += (t4.w < tj || (t4.w == tj && rb + 3 < jloc)) ? 1 : 0;
        cntK += (t4.x <= negc) ? 1 : 0;
        cntK += (t4.y <= negc) ? 1 : 0;
        cntK += (t4.z <= negc) ? 1 : 0;
        cntK += (t4.w <= negc) ? 1 : 0;
    }
    rankPart[part * 8192 + j] = cntR;
    kPart[part * 8192 + j]    = cntK;
}

// C: sum partials (LDS-staged), scatter weighted rows into rank order, emit kk
__global__ __launch_bounds__(256) void kC_scatter(
        const float* __restrict__ Wh, const float* __restrict__ s2,
        const int* __restrict__ rankPart, const int* __restrict__ kPart,
        float* __restrict__ Rpos, float* __restrict__ Rneg,
        float* __restrict__ spos, float* __restrict__ sneg,
        int* __restrict__ kk) {
    __shared__ int rsl[512], ksl[512];
    __shared__ int rsum[16], ksum[16];
    int tid = threadIdx.x;
    int j0 = blockIdx.x * 16;
    for (int idx = tid; idx < 512; idx += 256) {
        int p = idx >> 4, jj = idx & 15;
        rsl[idx] = rankPart[p * 8192 + j0 + jj];
        ksl[idx] = kPart[p * 8192 + j0 + jj];
    }
    __syncthreads();
    if (tid < 16) {
        int a = 0, bq = 0;
        #pragma unroll
        for (int p = 0; p < 32; ++p) { a += rsl[p * 16 + tid]; bq += ksl[p * 16 + tid]; }
        rsum[tid] = a; ksum[tid] = bq;
    }
    __syncthreads();
    int jj = tid >> 4, h4 = tid & 15;
    int j = j0 + jj;
    int r = rsum[jj];
    float t = s2[j];
    float e1 = expf(t), e2 = expf(0.2f * t);
    float4 wv = ((const float4*)Wh)[j * 16 + h4];
    ((float4*)Rpos)[r * 16 + h4] = make_float4(e1 * wv.x, e1 * wv.y, e1 * wv.z, e1 * wv.w);
    ((float4*)Rneg)[r * 16 + h4] = make_float4(e2 * wv.x, e2 * wv.y, e2 * wv.z, e2 * wv.w);
    if (h4 == 0) { spos[r] = e1; sneg[r] = e2; kk[j] = ksum[jj]; }
}

// D: per-chunk sums — 4 waves × 32 register rows
__global__ __launch_bounds__(256) void kD_csum(
        const float* __restrict__ Rpos, const float* __restrict__ Rneg,
        const float* __restrict__ spos, const float* __restrict__ sneg,
        float* __restrict__ csP, float* __restrict__ csN,
        float* __restrict__ csp, float* __restrict__ csn) {
    __shared__ float ldsP[4][64], ldsN[4][64];
    int ch = blockIdx.x, tid = threadIdx.x;
    int h = tid & 63, w = tid >> 6;
    int rb = ch * 128 + w * 32;
    double aP = 0.0, aN = 0.0;
    #pragma unroll
    for (int r = 0; r < 32; ++r) {
        aP += Rpos[(rb + r) * 64 + h];
        aN += Rneg[(rb + r) * 64 + h];
    }
    ldsP[w][h] = (float)aP; ldsN[w][h] = (float)aN;
    __syncthreads();
    if (w == 0) {
        csP[ch * 64 + h] = ldsP[0][h] + ldsP[1][h] + ldsP[2][h] + ldsP[3][h];
    } else if (w == 1) {
        csN[ch * 64 + h] = ldsN[0][h] + ldsN[1][h] + ldsN[2][h] + ldsN[3][h];
    } else if (w == 2) {
        float v = spos[ch * 128 + h] + spos[ch * 128 + 64 + h];
        v = wred_sum(v);
        if (h == 0) csp[ch] = v;
    } else {
        float v = sneg[ch * 128 + h] + sneg[ch * 128 + 64 + h];
        v = wred_sum(v);
        if (h == 0) csn[ch] = v;
    }
}

// E: expand to full exclusive prefixes — register-batched
__global__ __launch_bounds__(256) void kE_expand(
        const float* __restrict__ Rpos, const float* __restrict__ Rneg,
        const float* __restrict__ spos, const float* __restrict__ sneg,
        const float* __restrict__ csP, const float* __restrict__ csN,
        const float* __restrict__ csp, const float* __restrict__ csn,
        float* __restrict__ Ppos, float* __restrict__ Pneg,
        float* __restrict__ ppos, float* __restrict__ pneg) {
    __shared__ float ldsA[4][64], ldsB[4][64];
    __shared__ float cbPs[64], cbNs[64];
    int ch = blockIdx.x, tid = threadIdx.x;
    int h = tid & 63, w = tid >> 6;
    double bp = 0.0, bn = 0.0;
    for (int p = w; p < ch; p += 4) { bp += csP[p * 64 + h]; bn += csN[p * 64 + h]; }
    ldsA[w][h] = (float)bp; ldsB[w][h] = (float)bn;
    __syncthreads();
    if (w == 0) {
        cbPs[h] = ldsA[0][h] + ldsA[1][h] + ldsA[2][h] + ldsA[3][h];
        cbNs[h] = ldsB[0][h] + ldsB[1][h] + ldsB[2][h] + ldsB[3][h];
    }
    __syncthreads();
    float cbP = cbPs[h], cbN = cbNs[h];
    int rb = ch * 128 + w * 32;
    float v[32];
    #pragma unroll
    for (int r = 0; r < 32; ++r) v[r] = Rpos[(rb + r) * 64 + h];
    double acc = 0.0;
    #pragma unroll
    for (int r = 0; r < 32; ++r) acc += v[r];
    ldsA[w][h] = (float)acc;
    __syncthreads();
    float off = cbP;
    #pragma unroll
    for (int w2 = 0; w2 < 4; ++w2) if (w2 < w) off += ldsA[w2][h];
    double a2_ = 0.0;
    #pragma unroll
    for (int r = 0; r < 32; ++r) { Ppos[(rb + r) * 64 + h] = off + (float)a2_; a2_ += v[r]; }
    if (ch == 63 && w == 3) Ppos[Nn * 64 + h] = off + (float)a2_;
    __syncthreads();
    #pragma unroll
    for (int r = 0; r < 32; ++r) v[r] = Rneg[(rb + r) * 64 + h];
    acc = 0.0;
    #pragma unroll
    for (int r = 0; r < 32; ++r) acc += v[r];
    ldsB[w][h] = (float)acc;
    __syncthreads();
    off = cbN;
    #pragma unroll
    for (int w2 = 0; w2 < 4; ++w2) if (w2 < w) off += ldsB[w2][h];
    a2_ = 0.0;
    #pragma unroll
    for (int r = 0; r < 32; ++r) { Pneg[(rb + r) * 64 + h] = off + (float)a2_; a2_ += v[r]; }
    if (ch == 63 && w == 3) Pneg[Nn * 64 + h] = off + (float)a2_;
    if (w == 0) {
        int lane = h;
        float bs = (lane < ch) ? csp[lane] : 0.f;
        bs = wred_sum(bs);
        float v0 = spos[ch * 128 + lane], v1 = spos[ch * 128 + 64 + lane];
        float i0 = wscan_incl(v0, lane);
        float t0 = __shfl(i0, 63);
        float i1 = wscan_incl(v1, lane);
        ppos[ch * 128 + lane]      = bs + i0 - v0;
        ppos[ch * 128 + 64 + lane] = bs + t0 + i1 - v1;
        if (ch == 63 && lane == 63) ppos[Nn] = bs + t0 + i1;
    } else if (w == 1) {
        int lane = h;
        float bs = (lane < ch) ? csn[lane] : 0.f;
        bs = wred_sum(bs);
        float v0 = sneg[ch * 128 + lane], v1 = sneg[ch * 128 + 64 + lane];
        float i0 = wscan_incl(v0, lane);
        float t0 = __shfl(i0, 63);
        float i1 = wscan_incl(v1, lane);
        pneg[ch * 128 + lane]      = bs + i0 - v0;
        pneg[ch * 128 + 64 + lane] = bs + t0 + i1 - v1;
        if (ch == 63 && lane == 63) pneg[Nn] = bs + t0 + i1;
    }
}

// F: per-node hp via precomputed split index kk[n] + prefix lookups, time-attn -> h2
__global__ __launch_bounds__(256) void kF_node(
        const float* __restrict__ s1, const int* __restrict__ kk,
        const float* __restrict__ pmax, const float* __restrict__ gab,
        const float* __restrict__ Ppos, const float* __restrict__ Pneg,
        const float* __restrict__ ppos, const float* __restrict__ pneg,
        const float* __restrict__ taW, const float* __restrict__ tab,
        float* __restrict__ h2) {
    __shared__ float4 wt4[1024];   // taW: [kk4*64 + h]
    __shared__ float hl[16 * 64];
    int tid = threadIdx.x;
    for (int fidx = tid; fidx < 1024; fidx += 256) {
        int h_ = fidx >> 4, kk4 = fidx & 15;
        wt4[kk4 * 64 + h_] = ((const float4*)taW)[fidx];
    }
    float tmx = pmax[tid & 31];
    tmx = wred_max(tmx);
    __syncthreads();
    int h = tid & 63, w = tid >> 6;
    float gabv = gab[0];
    float tabv = tab[h];
    float Tp  = Ppos[Nn * 64 + h];
    float ppT = ppos[Nn];
    for (int r = 0; r < 4; ++r) {
        int n = blockIdx.x * 16 + w * 4 + r;
        float c = s1[n] + gabv;
        int k = kk[n];
        float z = c + tmx;
        float m = (z >= 0.f) ? z : 0.2f * z;
        float E1 = expf(c - m), E2 = expf(0.2f * c - m);
        float Pp = Ppos[k * 64 + h], Pn = Pneg[k * 64 + h];
        float num = E1 * (Tp - Pp) + E2 * Pn;
        float den = E1 * (ppT - ppos[k]) + E2 * pneg[k];
        float hp = num / den;
        int slot = w * 4 + r;
        hl[slot * 64 + h] = hp;
        float vv = tabv;
        const float4* hlr = (const float4*)&hl[slot * 64];
        #pragma unroll
        for (int kk4 = 0; kk4 < 16; ++kk4) {
            float4 w4 = wt4[kk4 * 64 + h];
            float4 x4 = hlr[kk4];
            vv += w4.x * x4.x + w4.y * x4.y + w4.z * x4.z + w4.w * x4.w;
        }
        float mx = wred_max(vv);
        float e = expf(vv - mx);
        float se = wred_sum(e);
        h2[n * 64 + h] = hp * (e / se);
    }
}

// G: mean over S + MLP head -> out
__global__ __launch_bounds__(256) void kG_pool(
        const float* __restrict__ h2,
        const float* __restrict__ p1W, const float* __restrict__ p1b,
        const float* __restrict__ p2W, const float* __restrict__ p2b,
        float* __restrict__ out) {
    __shared__ float pacc[4 * 64];
    __shared__ float pl[64];
    __shared__ float p1s[32 * 65];
    int tid = threadIdx.x, b = blockIdx.x;
    int w = tid >> 6, h = tid & 63;
    for (int idx = tid; idx < 2048; idx += 256) {
        int q = idx >> 6, kq = idx & 63;
        p1s[q * 65 + kq] = p1W[idx];
    }
    float a = 0.f;
    for (int s = w * 32; s < w * 32 + 32; ++s) a += h2[(b * Sd + s) * 64 + h];
    pacc[w * 64 + h] = a;
    __syncthreads();
    if (w == 0) {
        float pooled = (pacc[h] + pacc[64 + h] + pacc[128 + h] + pacc[192 + h]) * (1.f / 128.f);
        pl[h] = pooled;
        float val = 0.f;
        if (h < 32) {
            float acc = p1b[h];
            #pragma unroll
            for (int kq = 0; kq < 64; ++kq) acc += p1s[h * 65 + kq] * pl[kq];
            val = p2W[h] * fmaxf(acc, 0.f);
        }
        val = wred_sum(val);
        if (h == 0) out[b] = val + p2b[0];
    }
}

extern "C" void kernel_launch(void* const* d_in, const int* in_sizes, int n_in,
                              void* d_out, int out_size, void* d_ws, size_t ws_size,
                              hipStream_t stream) {
    const float* x    = (const float*)d_in[0];
    const float* c1w  = (const float*)d_in[1];
    const float* c1b  = (const float*)d_in[2];
    const float* b1g  = (const float*)d_in[3];
    const float* b1b  = (const float*)d_in[4];
    const float* b1m  = (const float*)d_in[5];
    const float* b1v  = (const float*)d_in[6];
    const float* c2w  = (const float*)d_in[7];
    const float* c2b  = (const float*)d_in[8];
    const float* b2g  = (const float*)d_in[9];
    const float* b2b  = (const float*)d_in[10];
    const float* b2m  = (const float*)d_in[11];
    const float* b2v  = (const float*)d_in[12];
    const float* gW   = (const float*)d_in[13];
    const float* gWb  = (const float*)d_in[14];
    const float* ga1  = (const float*)d_in[15];
    const float* ga2  = (const float*)d_in[16];
    const float* gab  = (const float*)d_in[17];
    const float* taW  = (const float*)d_in[18];
    const float* tab  = (const float*)d_in[19];
    const float* p1W  = (const float*)d_in[20];
    const float* p1b  = (const float*)d_in[21];
    const float* p2W  = (const float*)d_in[22];
    const float* p2b  = (const float*)d_in[23];
    float* out = (float*)d_out;

    float* ws = (float*)d_ws;
    float* Wh      = ws;                    // 524288
    float* s1      = Wh + 524288;           // 8192
    float* s2v     = s1 + 8192;             // 8192
    float* spos    = s2v + 8192;            // 8192
    float* sneg    = spos + 8192;           // 8192
    float* ppos    = sneg + 8192;           // 8256 (8193 used)
    float* pneg    = ppos + 8256;           // 8256
    float* csP     = pneg + 8256;           // 4096
    float* csN     = csP + 4096;            // 4096
    float* csp     = csN + 4096;            // 64
    float* csn     = csp + 64;              // 64
    float* pmax    = csn + 64;              // 64 (32 used)
    int*   kk      = (int*)(pmax + 64);     // 8192
    int*   rankPart= kk + 8192;             // 32*8192
    int*   kPart   = rankPart + 262144;     // 32*8192
    float* Rpos    = (float*)(kPart + 262144);  // 524288
    float* Rneg    = Rpos + 524288;         // 524288
    float* Ppos    = Rneg + 524288;         // 524352 (8193 rows)
    float* Pneg    = Ppos + 524352;         // 524352
    float* h2      = Rpos;                  // alias: Rpos dead after E

    kA_feat_wh<<<256, 256, 0, stream>>>(x, c1w, c1b, b1g, b1b, b1m, b1v,
                                        c2w, c2b, b2g, b2b, b2m, b2v,
                                        gW, gWb, ga1, ga2, Wh, s1, s2v);
    kB_rank<<<1024, 256, 0, stream>>>(s2v, s1, gab, rankPart, kPart, pmax);
    kC_scatter<<<512, 256, 0, stream>>>(Wh, s2v, rankPart, kPart,
                                        Rpos, Rneg, spos, sneg, kk);
    kD_csum<<<64, 256, 0, stream>>>(Rpos, Rneg, spos, sneg, csP, csN, csp, csn);
    kE_expand<<<64, 256, 0, stream>>>(Rpos, Rneg, spos, sneg, csP, csN, csp, csn,
                                      Ppos, Pneg, ppos, pneg);
    kF_node<<<512, 256, 0, stream>>>(s1, kk, pmax, gab, Ppos, Pneg, ppos, pneg,
                                     taW, tab, h2);
    kG_pool<<<64, 256, 0, stream>>>(h2, p1W, p1b, p2W, p2b, out);
}